// Round 9
// baseline (245.054 us; speedup 1.0000x reference)
//
#include <hip/hip_runtime.h>

// Problem constants
static constexpr int Nn_ = 32, Cc_ = 64, Hh_ = 64, Ww_ = 64;
static constexpr int K_ = 512;
static constexpr int HW_ = Hh_ * Ww_;             // 4096
static constexpr int CHW_ = Cc_ * HW_;            // 262144
static constexpr int T_ = Nn_ * Hh_ * Ww_;        // 131072 tokens
static constexpr int OUT_ELEMS = Nn_ * Cc_ * Hh_ * Ww_;  // 8388608
// d_out layout: [out][codebook_new (32768)][N_new (512)][m_new (32768)]
static constexpr int OFF_CB = OUT_ELEMS;
static constexpr int OFF_N  = OUT_ELEMS + 32768;
static constexpr int OFF_M  = OUT_ELEMS + 32768 + 512;

// ws layout (float indices), total ~1.13MB (was 35MB):
// [WS_ACC, +33280)    merged accumulator [psum 512*64][pcnt 512] (k_zero'd)
// [WS_FIXCNT]         fix counter (int, k_zero'd)
// [WS_FIXLIST, +T)    uncertified token ids
// [WS_IDX, +T)        idx per token (int)
static constexpr int WS_ACC     = 0;
static constexpr int ACC_CNT    = 32768;
static constexpr int WS_FIXCNT  = 33280;
static constexpr int WS_FIXLIST = 33284;                  // +T_ -> 164356
static constexpr int WS_IDX     = 164356;                 // +T_ -> 295428

static constexpr float THETA = 0.002f;  // cert threshold; fp16x3 worst error
                                        // (lo*lo drop + accum rounding) < 5.6e-4

typedef _Float16 half8  __attribute__((ext_vector_type(8)));
typedef float    f32x16 __attribute__((ext_vector_type(16)));

// K0: zero acc + pcnt + fixcnt each replay (graph-safe; R2-R4-proven shape).
// 8321 float4 = floats [0, 33284) = psum + pcnt + fixcnt (+3 pad).
__global__ __launch_bounds__(256) void k_zero(float* __restrict__ ws) {
    int i = blockIdx.x * 256 + threadIdx.x;
    if (i < 8321) ((float4*)ws)[i] = make_float4(0.f, 0.f, 0.f, 0.f);
}

// K1: fp16x3 split MFMA assign, now SELF-CONTAINED (k_prep deleted):
// cnorm512 computed per block from L2-hot cb; cb tiles read as fp32 and
// hi/lo-split in-register during staging (R8 ledger: k_prep + its kernel
// boundary cost more than the ~0.5us aggregate this adds).
// LDS diet: xs_l region is DEAD after B-fragment load -> cb double-buffer
// overlays it. 52224 -> 35840 B = 4 blocks/CU (was 3).
// qt epilogue stride 132->131 words (132 % 32 == 4 -> 8-way write conflict,
// the measured 2.23M SQ_LDS_BANK_CONFLICT; 131 % 32 == 3, coprime -> free).
__global__ __launch_bounds__(256, 4) void k_assign(const float* __restrict__ x,
                                                   const float* __restrict__ cb,
                                                   float* __restrict__ ws,
                                                   float* __restrict__ out) {
    __shared__ alignas(16) unsigned char smem[35840];
    // [0,16384) xs_h | [16384,32768) xs_l, then cb dbuf (2 x 8KB)
    // [32768,34816) cnorm_s (512 f32) | [34816,35328) bi_s
    // qt epilogue overlays [0,33536) as float[64][131]
    float* cn_s = (float*)(smem + 32768);
    int*   bi_s = (int*)(smem + 34816);

    const int b    = blockIdx.x;
    const int tid  = threadIdx.x;
    const int lane = tid & 63;
    const int wv   = tid >> 6;
    const int row0 = 2 * b, row1 = 2 * b + 1;
    const int xb0 = (row0 >> 6) * CHW_ + (row0 & 63) * Ww_;
    const int xb1 = (row1 >> 6) * CHW_ + (row1 & 63) * Ww_;

    // ---- stage x -> fp16 hi/lo LDS tile (swizzled; R5-R8 validated) ----
    {
        const int s  = tid & 31;        // token-quad id
        const int c8 = tid >> 5;        // channel octet
        const int r  = s >> 4, wq = s & 15;
        half8 hp[4], lp[4];
#pragma unroll
        for (int stp = 0; stp < 8; ++stp) {
            int ch = c8 * 8 + stp;
            float4 v = *(const float4*)(x + (r ? xb1 : xb0) + ch * HW_ + 4 * wq);
            float vv[4] = {v.x, v.y, v.z, v.w};
#pragma unroll
            for (int j = 0; j < 4; ++j) {
                _Float16 h = (_Float16)vv[j];
                _Float16 lo = (_Float16)(vv[j] - (float)h);
                hp[j][stp] = h; lp[j][stp] = lo;
            }
        }
        const int blk = c8 ^ (wq & 7);
#pragma unroll
        for (int j = 0; j < 4; ++j) {
            int tt = 64 * r + 4 * wq + j;
            *(half8*)(smem + tt * 128 + blk * 16) = hp[j];
            *(half8*)(smem + 16384 + tt * 128 + blk * 16) = lp[j];
        }
    }
    // ---- cnorm for all 512 codewords (cb L2-hot: 128KB) ----
    for (int r2 = tid; r2 < 512; r2 += 256) {
        const float4* cr = (const float4*)(cb + r2 * 64);
        float a = 0.f;
#pragma unroll
        for (int i = 0; i < 16; ++i) {
            float4 v = cr[i];
            a = fmaf(v.x, v.x, a); a = fmaf(v.y, v.y, a);
            a = fmaf(v.z, v.z, a); a = fmaf(v.w, v.w, a);
        }
        cn_s[r2] = a;
    }
    __syncthreads();                     // xs + cn_s ready

    // ---- per-wave B-fragments (x), loaded once ----
    const int tb = 32 * wv + (lane & 31);   // local token of this lane
    const int hi = lane >> 5;
    half8 bh[4], bl[4];
    {
        const int tsw = (tb >> 2) & 7;
#pragma unroll
        for (int ks = 0; ks < 4; ++ks) {
            int blk = (2 * ks + hi) ^ tsw;
            bh[ks] = *(const half8*)(smem + tb * 128 + blk * 16);
            bl[ks] = *(const half8*)(smem + 16384 + tb * 128 + blk * 16);
        }
    }
    __syncthreads();                     // xs_l reads done -> region reusable

    // ---- stage cb tile 0 (fp32 -> hi/lo split in-register) into buf0 ----
    {
        int r = tid >> 3, g8 = tid & 7, p = g8 ^ (r & 7);
        const float* src = cb + r * 64 + g8 * 8;
        float4 a0 = *(const float4*)src, a1 = *(const float4*)(src + 4);
        float vv[8] = {a0.x, a0.y, a0.z, a0.w, a1.x, a1.y, a1.z, a1.w};
        half8 hh, ll;
#pragma unroll
        for (int j = 0; j < 8; ++j) {
            _Float16 h = (_Float16)vv[j];
            hh[j] = h; ll[j] = (_Float16)(vv[j] - (float)h);
        }
        *(half8*)(smem + 16384 + r * 128 + p * 16) = hh;
        *(half8*)(smem + 16384 + 4096 + r * 128 + p * 16) = ll;
    }
    __syncthreads();                     // tile0 ready

    // ---- main loop: 16 cw-tiles, cb from LDS dbuf ----
    const int R = lane & 31;
    float bd1 = __int_as_float(0x7f800000);
    float bd2 = __int_as_float(0x7f800000);
    int bk1 = 0;

#pragma unroll 1
    for (int t = 0; t < 16; ++t) {
        const int cur = t & 1;
        float4 p0, p1;
        if (t < 15) {                    // T14: issue next-tile fp32 loads early
            const float* src = cb + ((t + 1) * 32 + (tid >> 3)) * 64 + (tid & 7) * 8;
            p0 = *(const float4*)src; p1 = *(const float4*)(src + 4);
        }
        const char* cb_b = (const char*)smem + 16384 + cur * 8192;
        half8 ah[4], al[4];
#pragma unroll
        for (int ks = 0; ks < 4; ++ks) {
            int pI = (2 * ks + hi) ^ (R & 7);
            ah[ks] = *(const half8*)(cb_b + R * 128 + pI * 16);
            al[ks] = *(const half8*)(cb_b + 4096 + R * 128 + pI * 16);
        }
        f32x16 acc = {0.f,0.f,0.f,0.f, 0.f,0.f,0.f,0.f,
                      0.f,0.f,0.f,0.f, 0.f,0.f,0.f,0.f};
#pragma unroll
        for (int ks = 0; ks < 4; ++ks) {
            acc = __builtin_amdgcn_mfma_f32_32x32x16_f16(ah[ks], bh[ks], acc, 0, 0, 0);
            acc = __builtin_amdgcn_mfma_f32_32x32x16_f16(ah[ks], bl[ks], acc, 0, 0, 0);
            acc = __builtin_amdgcn_mfma_f32_32x32x16_f16(al[ks], bh[ks], acc, 0, 0, 0);
        }
        // fold: d = cnorm - 2*dot; cn_s read is a 2-group LDS broadcast
        const int kt0 = t * 32 + 4 * hi;
        const int tb16 = t << 4;
#pragma unroll
        for (int j = 0; j < 16; ++j) {
            float cn = cn_s[kt0 + (j & 3) + 8 * (j >> 2)];
            float d = fmaf(-2.0f, acc[j], cn);
            int kid = tb16 | j;                 // k-order-consistent packed id
            bool lt = d < bd1;
            bd2 = lt ? bd1 : fminf(bd2, d);
            bk1 = lt ? kid : bk1;
            bd1 = fminf(bd1, d);
        }
        if (t < 15) {                    // split + write prefetched tile
            int r = tid >> 3, g8 = tid & 7, p = g8 ^ (r & 7);
            float vv[8] = {p0.x, p0.y, p0.z, p0.w, p1.x, p1.y, p1.z, p1.w};
            half8 hh, ll;
#pragma unroll
            for (int j = 0; j < 8; ++j) {
                _Float16 h = (_Float16)vv[j];
                hh[j] = h; ll[j] = (_Float16)(vv[j] - (float)h);
            }
            char* nb = (char*)smem + 16384 + (cur ^ 1) * 8192;
            *(half8*)(nb + r * 128 + p * 16) = hh;
            *(half8*)(nb + 4096 + r * 128 + p * 16) = ll;
        }
        __syncthreads();
    }

    // ---- decode + cross-lane (l ^ 32) merge; lanes<32 publish ----
    {
        int t0 = bk1 >> 4, j0 = bk1 & 15;
        int rk = 32 * t0 + (j0 & 3) + 8 * (j0 >> 2) + 4 * hi;
        unsigned uf = __float_as_uint(bd1);
        uf = (uf & 0x80000000u) ? ~uf : (uf | 0x80000000u);
        unsigned long long me = ((unsigned long long)uf << 32) | (unsigned)rk;
        unsigned long long ot = (unsigned long long)__shfl_xor((long long)me, 32);
        float od1 = __shfl_xor(bd1, 32);
        float od2 = __shfl_xor(bd2, 32);
        unsigned long long m1 = (me < ot) ? me : ot;
        float d1m = fminf(bd1, od1);
        float d2m = fminf(fminf(bd2, od2), fmaxf(bd1, od1));
        if (hi == 0) {
            int k1 = (int)(m1 & 0xffffffffu);
            bi_s[tb] = k1;
            ((int*)(ws + WS_IDX))[128 * b + tb] = k1;   // plain coalesced store
            if (!((d2m - d1m) > THETA)) {
                int pos = atomicAdd((int*)(ws + WS_FIXCNT), 1);
                ((int*)(ws + WS_FIXLIST))[pos] = 128 * b + tb;   // global token id
            }
        }
    }
    __syncthreads();   // bi_s visible; all LDS reads done

    // ---- q gather + transpose + bulk out write; stride 131 (conflict-free) --
    float (*qt)[131] = (float(*)[131])smem;
#pragma unroll
    for (int jj = 0; jj < 32; ++jj) {
        int tt = wv * 32 + jj;
        qt[lane][tt] = cb[bi_s[tt] * 64 + lane];
    }
    __syncthreads();
#pragma unroll
    for (int r = 0; r < 2; ++r)
#pragma unroll
        for (int j = 0; j < 16; ++j) {
            int c = wv * 16 + j;
            out[(r ? xb1 : xb0) + c * HW_ + lane] = qt[c][64 * r + lane];
        }
}

// KF: exact fp32 rescan for uncertified tokens, 8-TOKEN BATCHED.
// R8 diagnosis: old version re-gathered each lane's cb row (128 scattered
// 256B-row float4 loads) PER TOKEN. Here each wave loads 8 tokens' x into
// LDS, then one cb-row sweep computes 8 dots + cnorm inline (d = |c|^2 -
// 2x.c in a single pass; no WS_CN needed) -> gather traffic / 8.
__global__ __launch_bounds__(256) void k_fix(const float* __restrict__ x,
                                             const float* __restrict__ cb,
                                             float* __restrict__ ws,
                                             float* __restrict__ out) {
    __shared__ float xw[4][8][64];      // 8KB; wave-private rows
    const int tid = threadIdx.x, wv = tid >> 6, lane = tid & 63;
    const int cnt = *(const int*)(ws + WS_FIXCNT);
    const int* list = (const int*)(ws + WS_FIXLIST);
    int* idxg = (int*)(ws + WS_IDX);

    for (int base = (blockIdx.x * 4 + wv) * 8; base < cnt; base += 256 * 4 * 8) {
        const int nt = min(8, cnt - base);
        int gg[8];
#pragma unroll
        for (int j = 0; j < 8; ++j) {
            gg[j] = 0;
            if (j < nt) {
                int g = list[base + j]; gg[j] = g;
                int n = g >> 12, hw = g & 4095;
                xw[wv][j][lane] = x[n * CHW_ + lane * HW_ + hw];
            }
        }
        // same-wave LDS RAW: compiler inserts lgkmcnt wait; no barrier needed
        unsigned long long best[8];
#pragma unroll
        for (int j = 0; j < 8; ++j) best[j] = ~0ull;

#pragma unroll 1
        for (int jj = 0; jj < 8; ++jj) {
            const int k = lane + 64 * jj;
            const float4* cr = (const float4*)(cb + k * 64);
            float cn = 0.f;
            float dt[8] = {0.f,0.f,0.f,0.f,0.f,0.f,0.f,0.f};
#pragma unroll
            for (int q = 0; q < 16; ++q) {
                float4 cv = cr[q];
                cn = fmaf(cv.x, cv.x, cn); cn = fmaf(cv.y, cv.y, cn);
                cn = fmaf(cv.z, cv.z, cn); cn = fmaf(cv.w, cv.w, cn);
#pragma unroll
                for (int j = 0; j < 8; ++j) {
                    float4 xv = *(const float4*)&xw[wv][j][4 * q];   // broadcast
                    dt[j] = fmaf(cv.x, xv.x, dt[j]);
                    dt[j] = fmaf(cv.y, xv.y, dt[j]);
                    dt[j] = fmaf(cv.z, xv.z, dt[j]);
                    dt[j] = fmaf(cv.w, xv.w, dt[j]);
                }
            }
#pragma unroll
            for (int j = 0; j < 8; ++j) {
                float d = fmaf(-2.0f, dt[j], cn);
                unsigned uf = __float_as_uint(d);
                uf = (uf & 0x80000000u) ? ~uf : (uf | 0x80000000u);
                unsigned long long cd = ((unsigned long long)uf << 32) | (unsigned)k;
                if (cd < best[j]) best[j] = cd;
            }
        }
#pragma unroll
        for (int j = 0; j < 8; ++j) {
            if (j < nt) {               // wave-uniform guard (nt uniform)
                unsigned long long b2 = best[j];
#pragma unroll
                for (int m = 1; m < 64; m <<= 1) {
                    unsigned long long o = (unsigned long long)__shfl_xor((long long)b2, m);
                    if (o < b2) b2 = o;
                }
                int k1 = (int)(b2 & 0xffffffffu);
                int g = gg[j];
                int n = g >> 12, hw = g & 4095;
                out[n * CHW_ + lane * HW_ + hw] = cb[k1 * 64 + lane];
                if (lane == 0) idxg[g] = k1;
            }
        }
    }
}

// K2: one-hot MFMA stats (R7-validated core). Writeback changed: wave-wide
// CONSECUTIVE global atomics into the single 133KB accumulator, occupied
// rows only (R3/R4-validated shape, ~83K wave-ops) -> k_red + 34MB partial
// traffic deleted; k_final reads 133KB L2-hot.
__global__ __launch_bounds__(1024, 4) void k_stats(const float* __restrict__ x,
                                                   const float* __restrict__ ws_ro,
                                                   float* __restrict__ ws,
                                                   int TPB) {
    __shared__ float xt[2][64][65];     // 33280 B, double-buffered
    __shared__ float pcnt[512];
    __shared__ int   idx_s[512];

    const int tid  = threadIdx.x;
    const int bid  = blockIdx.x;
    const int wv   = tid >> 6;          // 0..15 == k-tile
    const int lane = tid & 63;
    const int hi   = lane >> 5;
    const int m    = lane & 31;
    const int NCH  = TPB >> 6;          // 64-token chunks per block

    f32x16 acc0 = {0.f,0.f,0.f,0.f, 0.f,0.f,0.f,0.f,
                   0.f,0.f,0.f,0.f, 0.f,0.f,0.f,0.f};   // c-tile 0
    f32x16 acc1 = acc0;                                  // c-tile 1

    if (tid < 512) pcnt[tid] = 0.f;
    const int* __restrict__ idxg = (const int*)(ws_ro + WS_IDX);

    const int cS = tid >> 4, tq = tid & 15;             // stage mapping
    {   // prologue: stage chunk 0 into xt[0]
        int tok0 = bid * TPB;
        int n = tok0 >> 12, hw0 = tok0 & 4095;
        float4 v = *(const float4*)(x + n * CHW_ + cS * HW_ + hw0 + 4 * tq);
        xt[0][4 * tq + 0][cS] = v.x;
        xt[0][4 * tq + 1][cS] = v.y;
        xt[0][4 * tq + 2][cS] = v.z;
        xt[0][4 * tq + 3][cS] = v.w;
    }

    int cur = 0;
    int k0 = 0;
    const int kb = (wv << 5) + m;       // this lane's codeword id

#pragma unroll 1
    for (int cc = 0; cc < NCH; ++cc) {
        const bool hasnext = (cc + 1 < NCH);
        float4 v;
        if (hasnext) {                  // T14: issue next-chunk loads early
            int tok0 = bid * TPB + (cc + 1) * 64;
            int n = tok0 >> 12, hw0 = tok0 & 4095;
            v = *(const float4*)(x + n * CHW_ + cS * HW_ + hw0 + 4 * tq);
        }
        if ((cc & 7) == 0 && tid < 512)
            k0 = idxg[bid * TPB + (cc >> 3) * 512 + tid];
        __syncthreads();                // xt[cur] writes + prev idx reads done
        if ((cc & 7) == 0) {
            if (tid < 512) { idx_s[tid] = k0; atomicAdd(&pcnt[k0], 1.0f); }
            __syncthreads();            // idx_s published
        }

        // 4 MFMA steps of 16 tokens each
#pragma unroll
        for (int st = 0; st < 4; ++st) {
            const int t0 = st * 16 + 8 * hi;   // token offset within chunk
            int ii[8];
#pragma unroll
            for (int j = 0; j < 8; ++j)
                ii[j] = idx_s[((cc & 7) << 6) + t0 + j];   // broadcast reads
            half8 bh0, bl0, bh1, bl1;
#pragma unroll
            for (int j = 0; j < 8; ++j) {      // conflict-free: bank=(t0+j+m)%32
                float f0 = xt[cur][t0 + j][m];
                float f1 = xt[cur][t0 + j][32 + m];
                _Float16 h0 = (_Float16)f0;
                _Float16 h1 = (_Float16)f1;
                bh0[j] = h0; bl0[j] = (_Float16)(f0 - (float)h0);
                bh1[j] = h1; bl1[j] = (_Float16)(f1 - (float)h1);
            }
            half8 ah;
#pragma unroll
            for (int j = 0; j < 8; ++j)
                ah[j] = (ii[j] == kb) ? (_Float16)1.0f : (_Float16)0.0f;
            acc0 = __builtin_amdgcn_mfma_f32_32x32x16_f16(ah, bh0, acc0, 0, 0, 0);
            acc0 = __builtin_amdgcn_mfma_f32_32x32x16_f16(ah, bl0, acc0, 0, 0, 0);
            acc1 = __builtin_amdgcn_mfma_f32_32x32x16_f16(ah, bh1, acc1, 0, 0, 0);
            acc1 = __builtin_amdgcn_mfma_f32_32x32x16_f16(ah, bl1, acc1, 0, 0, 0);
        }

        if (hasnext) {                  // write prefetched chunk to alt buf
            xt[cur ^ 1][4 * tq + 0][cS] = v.x;
            xt[cur ^ 1][4 * tq + 1][cS] = v.y;
            xt[cur ^ 1][4 * tq + 2][cS] = v.z;
            xt[cur ^ 1][4 * tq + 3][cS] = v.w;
            cur ^= 1;
        }
    }
    __syncthreads();                    // pcnt atomics drained

    // writeback: occupied rows only, wave-wide consecutive global atomics.
    // Per instr: lanes 0..31 -> row k(hi=0) c 0..31 / 32..63; lanes 32..63
    // -> row k(hi=1): 2 x 128B consecutive chunks, R3-measured-cheap shape.
    float* acc_g = ws + WS_ACC;
#pragma unroll
    for (int r = 0; r < 16; ++r) {
        int k = (wv << 5) + (r & 3) + 8 * (r >> 2) + 4 * hi;
        if (pcnt[k] > 0.f) {
            atomicAdd(acc_g + k * 64 + m,      acc0[r]);
            atomicAdd(acc_g + k * 64 + 32 + m, acc1[r]);
        }
    }
    if (tid < 512 && pcnt[tid] > 0.f)
        atomicAdd(acc_g + ACC_CNT + tid, pcnt[tid]);
}

// K3: finalize from the 133KB L2-hot merged accumulator (R4-era 3us shape).
__global__ __launch_bounds__(256) void k_final(const float* __restrict__ Ns,
                                               const float* __restrict__ ms,
                                               const float* __restrict__ ws,
                                               float* __restrict__ out) {
    int i = blockIdx.x * 256 + threadIdx.x;   // 0..32767
    int k = i >> 6, c = i & 63;

    const float* acc = ws + WS_ACC;
    float s   = acc[i];
    float cnt = acc[ACC_CNT + k];

    const float gamma = 0.99f;
    const float omg   = (float)(1.0 - 0.99);

    bool occ = cnt > 0.0f;
    float Nv = Ns[k];
    float Nnew = occ ? (Nv * gamma + cnt * omg) : Nv;

    float mv = ms[i];
    float mnew = occ ? (mv * gamma + s * omg) : mv;

    out[OFF_CB + i] = mnew / Nnew;
    out[OFF_M  + i] = mnew;
    if (c == 0) out[OFF_N + k] = Nnew;
}

extern "C" void kernel_launch(void* const* d_in, const int* in_sizes, int n_in,
                              void* d_out, int out_size, void* d_ws, size_t ws_size,
                              hipStream_t stream) {
    const float* x  = (const float*)d_in[0];
    const float* cb = (const float*)d_in[1];
    const float* Ns = (const float*)d_in[2];
    const float* ms = (const float*)d_in[3];
    float* out = (float*)d_out;
    float* ws  = (float*)d_ws;

    hipLaunchKernelGGL(k_zero,   dim3(33),   dim3(256),  0, stream, ws);
    hipLaunchKernelGGL(k_assign, dim3(1024), dim3(256),  0, stream, x, cb, ws, out);
    hipLaunchKernelGGL(k_fix,    dim3(256),  dim3(256),  0, stream, x, cb, ws, out);
    hipLaunchKernelGGL(k_stats,  dim3(256),  dim3(1024), 0, stream, x, ws, ws, 512);
    hipLaunchKernelGGL(k_final,  dim3(128),  dim3(256),  0, stream, Ns, ms, ws, out);
}